// Round 1
// baseline (1793.223 us; speedup 1.0000x reference)
//
#include <hip/hip_runtime.h>

typedef unsigned short u16;
typedef __attribute__((ext_vector_type(4))) float f32x4;
typedef __attribute__((ext_vector_type(8))) short bf16x8;

// ---------- helpers ----------
__device__ inline u16 f2bf(float f) {
    union { float f; unsigned int u; } v; v.f = f;
    unsigned int u = v.u;
    unsigned int r = (u + 0x7fffu + ((u >> 16) & 1u)) >> 16;
    return (u16)r;
}

// ---------- fp32 -> bf16 elementwise ----------
__global__ void cvt_kernel(const float* __restrict__ in, u16* __restrict__ out, int n4) {
    int i = blockIdx.x * blockDim.x + threadIdx.x;
    int stride = gridDim.x * blockDim.x;
    for (int idx = i; idx < n4; idx += stride) {
        float4 v = ((const float4*)in)[idx];
        ushort4 o;
        o.x = f2bf(v.x); o.y = f2bf(v.y); o.z = f2bf(v.z); o.w = f2bf(v.w);
        ((ushort4*)out)[idx] = o;
    }
}

// ---------- fp32 [K][N] -> bf16 [N][K] transpose+convert (K fixed 2048) ----------
__global__ void tcvt_kernel(const float* __restrict__ w, u16* __restrict__ wt, int N) {
    __shared__ float tile[64][65];
    int t = threadIdx.x;
    int tx = t & 63, ty = t >> 6;            // ty 0..3
    int k0 = blockIdx.y * 64, n0 = blockIdx.x * 64;
#pragma unroll
    for (int i = 0; i < 16; ++i)
        tile[ty * 16 + i][tx] = w[(size_t)(k0 + ty * 16 + i) * N + n0 + tx];
    __syncthreads();
#pragma unroll
    for (int i = 0; i < 16; ++i)
        wt[(size_t)(n0 + ty * 16 + i) * 2048 + k0 + tx] = f2bf(tile[tx][ty * 16 + i]);
}

// ---------- bf16 GEMM: C[M,N] = A[M,2048] * Bt[N,2048]^T ----------
// 128x128 tile, BK=32, 4 waves (2x2), 16x16x32 MFMA.
// C_F32: store float, else bf16.  C_T: store at col*ldc+row (transposed output).
template<bool C_F32, bool C_T>
__global__ __launch_bounds__(256, 2) void gemm_kernel(const u16* __restrict__ A,
                                                      const u16* __restrict__ Bt,
                                                      void* __restrict__ Cv, int ldc) {
    __shared__ __align__(16) u16 As[128][40];
    __shared__ __align__(16) u16 Bs[128][40];
    int tid = threadIdx.x;
    int lane = tid & 63, wid = tid >> 6;
    int lr = lane & 15, lg = lane >> 4;
    int wr = wid >> 1, wc = wid & 1;
    size_t m0 = (size_t)blockIdx.y * 128, n0 = (size_t)blockIdx.x * 128;

    int srow = tid >> 2, sg = tid & 3;       // srow 0..63 (+64), sg: 8-wide k-group
    const u16* ga = A + (m0 + srow) * 2048 + sg * 8;
    const u16* gb = Bt + (n0 + srow) * 2048 + sg * 8;

    f32x4 acc[4][4] = {};

    for (int k0 = 0; k0 < 2048; k0 += 32) {
        uint4 va0 = *(const uint4*)(ga + k0);
        uint4 va1 = *(const uint4*)(ga + (size_t)64 * 2048 + k0);
        uint4 vb0 = *(const uint4*)(gb + k0);
        uint4 vb1 = *(const uint4*)(gb + (size_t)64 * 2048 + k0);
        *(uint4*)&As[srow][sg * 8] = va0;
        *(uint4*)&As[srow + 64][sg * 8] = va1;
        *(uint4*)&Bs[srow][sg * 8] = vb0;
        *(uint4*)&Bs[srow + 64][sg * 8] = vb1;
        __syncthreads();
        bf16x8 af[4], bfr[4];
#pragma unroll
        for (int m = 0; m < 4; ++m) af[m] = *(const bf16x8*)&As[wr * 64 + m * 16 + lr][lg * 8];
#pragma unroll
        for (int n = 0; n < 4; ++n) bfr[n] = *(const bf16x8*)&Bs[wc * 64 + n * 16 + lr][lg * 8];
#pragma unroll
        for (int m = 0; m < 4; ++m)
#pragma unroll
            for (int n = 0; n < 4; ++n)
                acc[m][n] = __builtin_amdgcn_mfma_f32_16x16x32_bf16(af[m], bfr[n], acc[m][n], 0, 0, 0);
        __syncthreads();
    }

#pragma unroll
    for (int m = 0; m < 4; ++m)
#pragma unroll
        for (int n = 0; n < 4; ++n)
#pragma unroll
            for (int i = 0; i < 4; ++i) {
                size_t row = m0 + wr * 64 + m * 16 + lg * 4 + i;
                size_t col = n0 + wc * 64 + n * 16 + lr;
                float v = acc[m][n][i];
                size_t off = C_T ? (col * (size_t)ldc + row) : (row * (size_t)ldc + col);
                if (C_F32) ((float*)Cv)[off] = v;
                else       ((u16*)Cv)[off] = f2bf(v);
            }
}

// ---------- causal GQA flash attention ----------
// Q: [8192][2048] bf16 (row = b*4096+t, col = h*128+d)
// K: [8192][512]  bf16 (col = hkv*128+d)
// Vt: [512][8192] bf16 (row = hkv*128+d, col = b*4096+t)
// O: [8192][2048] bf16
__global__ __launch_bounds__(256, 2) void attn_kernel(const u16* __restrict__ Q,
                                                      const u16* __restrict__ K,
                                                      const u16* __restrict__ Vt,
                                                      u16* __restrict__ O) {
    __shared__ __align__(16) u16 P[4][16][72];
    int tid = threadIdx.x;
    int lane = tid & 63, w = tid >> 6;
    int lr = lane & 15, lg = lane >> 4;
    int qt = blockIdx.x;                     // 0..63 (q tile of 64 rows)
    int bh = blockIdx.y;                     // 0..31
    int b = bh >> 4, h = bh & 15, hkv = h >> 2;
    int q0 = qt * 64;
    int qbase = q0 + w * 16;                 // this wave's first q row (within T)

    const u16* qp = Q + ((size_t)(b * 4096 + qbase)) * 2048 + h * 128;
    const u16* kp = K + ((size_t)(b * 4096)) * 512 + hkv * 128;
    const u16* vp = Vt + ((size_t)(hkv * 128)) * 8192 + (size_t)b * 4096;
    u16* op = O + ((size_t)(b * 4096 + qbase)) * 2048 + h * 128;

    bf16x8 qf[4];
#pragma unroll
    for (int kk = 0; kk < 4; ++kk)
        qf[kk] = *(const bf16x8*)(qp + (size_t)lr * 2048 + kk * 32 + lg * 8);

    float m_i[4], s_i[4];
    f32x4 oacc[8] = {};
#pragma unroll
    for (int i = 0; i < 4; ++i) { m_i[i] = -1e30f; s_i[i] = 0.f; }

    const float SCALE = 0.08838834764831845f; // 1/sqrt(128)

    for (int c = 0; c <= qt; ++c) {
        int kv0 = c * 64;
        f32x4 sacc[4] = {};
#pragma unroll
        for (int kk = 0; kk < 4; ++kk)
#pragma unroll
            for (int nt = 0; nt < 4; ++nt) {
                bf16x8 kf = *(const bf16x8*)(kp + (size_t)(kv0 + nt * 16 + lr) * 512 + kk * 32 + lg * 8);
                sacc[nt] = __builtin_amdgcn_mfma_f32_16x16x32_bf16(qf[kk], kf, sacc[nt], 0, 0, 0);
            }
        bool masked = (c == qt);
        float sv[4][4];
#pragma unroll
        for (int nt = 0; nt < 4; ++nt)
#pragma unroll
            for (int i = 0; i < 4; ++i) {
                float v = sacc[nt][i] * SCALE;
                if (masked && (kv0 + nt * 16 + lr > qbase + lg * 4 + i)) v = -1e30f;
                sv[nt][i] = v;
            }
        // ensure previous iteration's P reads completed before overwrite (cross-lane LDS hazard)
        asm volatile("s_waitcnt lgkmcnt(0)" ::: "memory");
#pragma unroll
        for (int i = 0; i < 4; ++i) {
            float cm = fmaxf(fmaxf(sv[0][i], sv[1][i]), fmaxf(sv[2][i], sv[3][i]));
#pragma unroll
            for (int off = 1; off < 16; off <<= 1) cm = fmaxf(cm, __shfl_xor(cm, off));
            float mn = fmaxf(m_i[i], cm);
            float sp = __expf(m_i[i] - mn);
            m_i[i] = mn;
            float rs = 0.f;
#pragma unroll
            for (int nt = 0; nt < 4; ++nt) {
                float p = __expf(sv[nt][i] - mn);
                rs += p;
                P[w][lg * 4 + i][nt * 16 + lr] = f2bf(p);
            }
#pragma unroll
            for (int off = 1; off < 16; off <<= 1) rs += __shfl_xor(rs, off);
            s_i[i] = s_i[i] * sp + rs;
#pragma unroll
            for (int dt = 0; dt < 8; ++dt) oacc[dt][i] *= sp;
        }
        // ensure P writes visible to cross-lane reads
        asm volatile("s_waitcnt lgkmcnt(0)" ::: "memory");
#pragma unroll
        for (int kk2 = 0; kk2 < 2; ++kk2) {
            bf16x8 pa = *(const bf16x8*)&P[w][lr][kk2 * 32 + lg * 8];
#pragma unroll
            for (int dt = 0; dt < 8; ++dt) {
                bf16x8 bv = *(const bf16x8*)(vp + (size_t)(dt * 16 + lr) * 8192 + kv0 + kk2 * 32 + lg * 8);
                oacc[dt] = __builtin_amdgcn_mfma_f32_16x16x32_bf16(pa, bv, oacc[dt], 0, 0, 0);
            }
        }
    }
#pragma unroll
    for (int dt = 0; dt < 8; ++dt)
#pragma unroll
        for (int i = 0; i < 4; ++i) {
            float v = oacc[dt][i] / s_i[i];
            op[(size_t)(lg * 4 + i) * 2048 + dt * 16 + lr] = f2bf(v);
        }
}

// ---------- launcher ----------
extern "C" void kernel_launch(void* const* d_in, const int* in_sizes, int n_in,
                              void* d_out, int out_size, void* d_ws, size_t ws_size,
                              hipStream_t stream) {
    const float* x  = (const float*)d_in[0];
    const float* wq = (const float*)d_in[1];
    const float* wk = (const float*)d_in[2];
    const float* wv = (const float*)d_in[3];
    const float* wo = (const float*)d_in[4];
    float* out = (float*)d_out;
    u16* ws = (u16*)d_ws;

    // workspace layout (elements of u16); ATTN aliases XB (x-bf16 dead after V gemm)
    u16* XB  = ws;                        // 16777216  [8192][2048]
    u16* WQT = ws + 16777216;             // 4194304   [2048][2048]
    u16* WKT = WQT + 4194304;             // 1048576   [512][2048]
    u16* WVT = WKT + 1048576;             // 1048576   [512][2048]
    u16* WOT = WVT + 1048576;             // 4194304   [2048][2048]
    u16* QB  = WOT + 4194304;             // 16777216  [8192][2048]
    u16* KB  = QB + 16777216;             // 4194304   [8192][512]
    u16* VT  = KB + 4194304;              // 4194304   [512][8192]
    u16* ATTN = XB;
    // total: 100 MiB of d_ws

    cvt_kernel<<<2048, 256, 0, stream>>>(x, XB, 16777216 / 4);
    tcvt_kernel<<<dim3(32, 32), 256, 0, stream>>>(wq, WQT, 2048);
    tcvt_kernel<<<dim3(8, 32), 256, 0, stream>>>(wk, WKT, 512);
    tcvt_kernel<<<dim3(8, 32), 256, 0, stream>>>(wv, WVT, 512);
    tcvt_kernel<<<dim3(32, 32), 256, 0, stream>>>(wo, WOT, 2048);

    gemm_kernel<false, false><<<dim3(16, 64), 256, 0, stream>>>(XB, WQT, (void*)QB, 2048);
    gemm_kernel<false, false><<<dim3(4, 64), 256, 0, stream>>>(XB, WKT, (void*)KB, 512);
    gemm_kernel<false, true ><<<dim3(4, 64), 256, 0, stream>>>(XB, WVT, (void*)VT, 8192);

    attn_kernel<<<dim3(64, 32), 256, 0, stream>>>(QB, KB, VT, ATTN);

    gemm_kernel<true, false><<<dim3(16, 64), 256, 0, stream>>>(ATTN, WOT, (void*)out, 2048);
}

// Round 3
// 759.038 us; speedup vs baseline: 2.3625x; 2.3625x over previous
//
#include <hip/hip_runtime.h>

typedef unsigned short u16;
typedef __attribute__((ext_vector_type(4))) float f32x4;
typedef __attribute__((ext_vector_type(8))) short bf16x8;

// ---------- helpers ----------
__device__ inline u16 f2bf(float f) {
    union { float f; unsigned int u; } v; v.f = f;
    unsigned int u = v.u;
    unsigned int r = (u + 0x7fffu + ((u >> 16) & 1u)) >> 16;
    return (u16)r;
}

// ---------- fp32 -> bf16 elementwise ----------
__global__ void cvt_kernel(const float* __restrict__ in, u16* __restrict__ out, int n4) {
    int i = blockIdx.x * blockDim.x + threadIdx.x;
    int stride = gridDim.x * blockDim.x;
    for (int idx = i; idx < n4; idx += stride) {
        float4 v = ((const float4*)in)[idx];
        ushort4 o;
        o.x = f2bf(v.x); o.y = f2bf(v.y); o.z = f2bf(v.z); o.w = f2bf(v.w);
        ((ushort4*)out)[idx] = o;
    }
}

// ---------- fp32 [K][N] -> bf16 [N][K] transpose+convert (K fixed 2048) ----------
__global__ void tcvt_kernel(const float* __restrict__ w, u16* __restrict__ wt, int N) {
    __shared__ float tile[64][65];
    int t = threadIdx.x;
    int tx = t & 63, ty = t >> 6;            // ty 0..3
    int k0 = blockIdx.y * 64, n0 = blockIdx.x * 64;
#pragma unroll
    for (int i = 0; i < 16; ++i)
        tile[ty * 16 + i][tx] = w[(size_t)(k0 + ty * 16 + i) * N + n0 + tx];
    __syncthreads();
#pragma unroll
    for (int i = 0; i < 16; ++i)
        wt[(size_t)(n0 + ty * 16 + i) * 2048 + k0 + tx] = f2bf(tile[tx][ty * 16 + i]);
}

// ---------- bf16 GEMM: C[M,N] = A[M,2048] * Bt[N,2048]^T ----------
template<bool C_F32, bool C_T>
__global__ __launch_bounds__(256, 2) void gemm_kernel(const u16* __restrict__ A,
                                                      const u16* __restrict__ Bt,
                                                      void* __restrict__ Cv, int ldc) {
    __shared__ __align__(16) u16 As[128][40];
    __shared__ __align__(16) u16 Bs[128][40];
    int tid = threadIdx.x;
    int lane = tid & 63, wid = tid >> 6;
    int lr = lane & 15, lg = lane >> 4;
    int wr = wid >> 1, wc = wid & 1;
    size_t m0 = (size_t)blockIdx.y * 128, n0 = (size_t)blockIdx.x * 128;

    int srow = tid >> 2, sg = tid & 3;
    const u16* ga = A + (m0 + srow) * 2048 + sg * 8;
    const u16* gb = Bt + (n0 + srow) * 2048 + sg * 8;

    f32x4 acc[4][4] = {};

    for (int k0 = 0; k0 < 2048; k0 += 32) {
        uint4 va0 = *(const uint4*)(ga + k0);
        uint4 va1 = *(const uint4*)(ga + (size_t)64 * 2048 + k0);
        uint4 vb0 = *(const uint4*)(gb + k0);
        uint4 vb1 = *(const uint4*)(gb + (size_t)64 * 2048 + k0);
        *(uint4*)&As[srow][sg * 8] = va0;
        *(uint4*)&As[srow + 64][sg * 8] = va1;
        *(uint4*)&Bs[srow][sg * 8] = vb0;
        *(uint4*)&Bs[srow + 64][sg * 8] = vb1;
        __syncthreads();
        bf16x8 af[4], bfr[4];
#pragma unroll
        for (int m = 0; m < 4; ++m) af[m] = *(const bf16x8*)&As[wr * 64 + m * 16 + lr][lg * 8];
#pragma unroll
        for (int n = 0; n < 4; ++n) bfr[n] = *(const bf16x8*)&Bs[wc * 64 + n * 16 + lr][lg * 8];
#pragma unroll
        for (int m = 0; m < 4; ++m)
#pragma unroll
            for (int n = 0; n < 4; ++n)
                acc[m][n] = __builtin_amdgcn_mfma_f32_16x16x32_bf16(af[m], bfr[n], acc[m][n], 0, 0, 0);
        __syncthreads();
    }

#pragma unroll
    for (int m = 0; m < 4; ++m)
#pragma unroll
        for (int n = 0; n < 4; ++n)
#pragma unroll
            for (int i = 0; i < 4; ++i) {
                size_t row = m0 + wr * 64 + m * 16 + lg * 4 + i;
                size_t col = n0 + wc * 64 + n * 16 + lr;
                float v = acc[m][n][i];
                size_t off = C_T ? (col * (size_t)ldc + row) : (row * (size_t)ldc + col);
                if (C_F32) ((float*)Cv)[off] = v;
                else       ((u16*)Cv)[off] = f2bf(v);
            }
}

// ---------- causal GQA flash attention (LDS-staged, double-buffered) ----------
// Q: [8192][2048] bf16, K: [8192][512] bf16, Vt: [512][8192] bf16, O: [8192][2048] bf16
// Block = 256 threads (4 waves). Each block processes TWO q-tiles of 128 rows
// (qt = bx and 31-bx) for load balance. Wave w: 32 q rows (two 16-row tiles).
// KV chunks of 64 staged into padded LDS, double-buffered (T14 async split).
__global__ __launch_bounds__(256, 2) void attn_kernel(const u16* __restrict__ Q,
                                                      const u16* __restrict__ K,
                                                      const u16* __restrict__ Vt,
                                                      u16* __restrict__ O) {
    __shared__ __align__(16) u16 Ks[2][64][136];   // pitch 272B
    __shared__ __align__(16) u16 Vs[2][128][72];   // pitch 144B
    __shared__ __align__(16) u16 P[4][16][72];     // pitch 144B (cols 0..63 used; 40 was OOB bug)
    int tid = threadIdx.x;
    int lane = tid & 63, w = tid >> 6;
    int lr = lane & 15, lg = lane >> 4;
    int bx = blockIdx.x;                     // 0..15
    int bh = blockIdx.y;                     // 0..31
    int b = bh >> 4, h = bh & 15, hkv = h >> 2;

    const u16* kp = K + (size_t)(b * 4096) * 512 + hkv * 128;
    const u16* vp = Vt + (size_t)(hkv * 128) * 8192 + (size_t)b * 4096;

    int skr = tid >> 4, skj = tid & 15;      // K staging
    int svd = tid >> 3, svj = tid & 7;       // V staging

    const float SCALE = 0.08838834764831845f; // 1/sqrt(128)

    for (int half = 0; half < 2; ++half) {
        int qt = half ? (31 - bx) : bx;
        int q0 = qt * 128;
        int nc = 2 * qt + 2;

        bf16x8 qf[2][4];
#pragma unroll
        for (int rt = 0; rt < 2; ++rt) {
            const u16* qp = Q + (size_t)(b * 4096 + q0 + w * 32 + rt * 16) * 2048 + h * 128;
#pragma unroll
            for (int kk = 0; kk < 4; ++kk)
                qf[rt][kk] = *(const bf16x8*)(qp + (size_t)lr * 2048 + kk * 32 + lg * 8);
        }

        float m_i[2][4], s_i[2][4];
        f32x4 oacc[2][8] = {};
#pragma unroll
        for (int rt = 0; rt < 2; ++rt)
#pragma unroll
            for (int i = 0; i < 4; ++i) { m_i[rt][i] = -1e30f; s_i[rt][i] = 0.f; }

        // prologue: stage chunk 0 into buffer 0
        {
            uint4 kreg[4], vreg[4];
#pragma unroll
            for (int i = 0; i < 4; ++i)
                kreg[i] = *(const uint4*)(kp + (size_t)(skr + i * 16) * 512 + skj * 8);
#pragma unroll
            for (int i = 0; i < 4; ++i)
                vreg[i] = *(const uint4*)(vp + (size_t)(svd + i * 32) * 8192 + svj * 8);
#pragma unroll
            for (int i = 0; i < 4; ++i) *(uint4*)&Ks[0][skr + i * 16][skj * 8] = kreg[i];
#pragma unroll
            for (int i = 0; i < 4; ++i) *(uint4*)&Vs[0][svd + i * 32][svj * 8] = vreg[i];
        }
        __syncthreads();

        int cur = 0;
        for (int c = 0; c < nc; ++c) {
            int kv0 = c * 64;
            bool have_next = (c + 1 < nc);
            uint4 kreg[4], vreg[4];
            if (have_next) {
                int kv1 = kv0 + 64;
#pragma unroll
                for (int i = 0; i < 4; ++i)
                    kreg[i] = *(const uint4*)(kp + (size_t)(kv1 + skr + i * 16) * 512 + skj * 8);
#pragma unroll
                for (int i = 0; i < 4; ++i)
                    vreg[i] = *(const uint4*)(vp + (size_t)(svd + i * 32) * 8192 + kv1 + svj * 8);
            }

            if (kv0 <= q0 + w * 32 + 31) {
#pragma unroll
                for (int rt = 0; rt < 2; ++rt) {
                    int qb = q0 + w * 32 + rt * 16;
                    if (kv0 > qb + 15) continue;
                    f32x4 sacc[4] = {};
#pragma unroll
                    for (int kk = 0; kk < 4; ++kk)
#pragma unroll
                        for (int nt = 0; nt < 4; ++nt) {
                            bf16x8 kf = *(const bf16x8*)&Ks[cur][nt * 16 + lr][kk * 32 + lg * 8];
                            sacc[nt] = __builtin_amdgcn_mfma_f32_16x16x32_bf16(qf[rt][kk], kf, sacc[nt], 0, 0, 0);
                        }
                    bool need_mask = (kv0 + 63 > qb);
                    float sv[4][4];
#pragma unroll
                    for (int nt = 0; nt < 4; ++nt)
#pragma unroll
                        for (int i = 0; i < 4; ++i) {
                            float v = sacc[nt][i] * SCALE;
                            if (need_mask && (kv0 + nt * 16 + lr > qb + lg * 4 + i)) v = -1e30f;
                            sv[nt][i] = v;
                        }
                    asm volatile("s_waitcnt lgkmcnt(0)" ::: "memory");
#pragma unroll
                    for (int i = 0; i < 4; ++i) {
                        float cm = fmaxf(fmaxf(sv[0][i], sv[1][i]), fmaxf(sv[2][i], sv[3][i]));
#pragma unroll
                        for (int off = 1; off < 16; off <<= 1) cm = fmaxf(cm, __shfl_xor(cm, off));
                        float mn = fmaxf(m_i[rt][i], cm);
                        float sp = __expf(m_i[rt][i] - mn);
                        m_i[rt][i] = mn;
                        float rs = 0.f;
#pragma unroll
                        for (int nt = 0; nt < 4; ++nt) {
                            float p = __expf(sv[nt][i] - mn);
                            rs += p;
                            P[w][lg * 4 + i][nt * 16 + lr] = f2bf(p);
                        }
#pragma unroll
                        for (int off = 1; off < 16; off <<= 1) rs += __shfl_xor(rs, off);
                        s_i[rt][i] = s_i[rt][i] * sp + rs;
#pragma unroll
                        for (int dt = 0; dt < 8; ++dt) oacc[rt][dt][i] *= sp;
                    }
                    asm volatile("s_waitcnt lgkmcnt(0)" ::: "memory");
                    __builtin_amdgcn_sched_barrier(0);
#pragma unroll
                    for (int kk2 = 0; kk2 < 2; ++kk2) {
                        bf16x8 pa = *(const bf16x8*)&P[w][lr][kk2 * 32 + lg * 8];
#pragma unroll
                        for (int dt = 0; dt < 8; ++dt) {
                            bf16x8 bv = *(const bf16x8*)&Vs[cur][dt * 16 + lr][kk2 * 32 + lg * 8];
                            oacc[rt][dt] = __builtin_amdgcn_mfma_f32_16x16x32_bf16(pa, bv, oacc[rt][dt], 0, 0, 0);
                        }
                    }
                }
            }

            if (have_next) {
                int nb = cur ^ 1;
#pragma unroll
                for (int i = 0; i < 4; ++i) *(uint4*)&Ks[nb][skr + i * 16][skj * 8] = kreg[i];
#pragma unroll
                for (int i = 0; i < 4; ++i) *(uint4*)&Vs[nb][svd + i * 32][svj * 8] = vreg[i];
            }
            __syncthreads();
            cur ^= 1;
        }

#pragma unroll
        for (int rt = 0; rt < 2; ++rt) {
            u16* op = O + (size_t)(b * 4096 + q0 + w * 32 + rt * 16) * 2048 + h * 128;
#pragma unroll
            for (int dt = 0; dt < 8; ++dt)
#pragma unroll
                for (int i = 0; i < 4; ++i) {
                    float v = oacc[rt][dt][i] / s_i[rt][i];
                    op[(size_t)(lg * 4 + i) * 2048 + dt * 16 + lr] = f2bf(v);
                }
        }
    }
}

// ---------- launcher ----------
extern "C" void kernel_launch(void* const* d_in, const int* in_sizes, int n_in,
                              void* d_out, int out_size, void* d_ws, size_t ws_size,
                              hipStream_t stream) {
    const float* x  = (const float*)d_in[0];
    const float* wq = (const float*)d_in[1];
    const float* wk = (const float*)d_in[2];
    const float* wv = (const float*)d_in[3];
    const float* wo = (const float*)d_in[4];
    float* out = (float*)d_out;
    u16* ws = (u16*)d_ws;

    u16* XB  = ws;                        // 16777216  [8192][2048]
    u16* WQT = ws + 16777216;             // 4194304   [2048][2048]
    u16* WKT = WQT + 4194304;             // 1048576   [512][2048]
    u16* WVT = WKT + 1048576;             // 1048576   [512][2048]
    u16* WOT = WVT + 1048576;             // 4194304   [2048][2048]
    u16* QB  = WOT + 4194304;             // 16777216  [8192][2048]
    u16* KB  = QB + 16777216;             // 4194304   [8192][512]
    u16* VT  = KB + 4194304;              // 4194304   [512][8192]
    u16* ATTN = XB;

    cvt_kernel<<<2048, 256, 0, stream>>>(x, XB, 16777216 / 4);
    tcvt_kernel<<<dim3(32, 32), 256, 0, stream>>>(wq, WQT, 2048);
    tcvt_kernel<<<dim3(8, 32), 256, 0, stream>>>(wk, WKT, 512);
    tcvt_kernel<<<dim3(8, 32), 256, 0, stream>>>(wv, WVT, 512);
    tcvt_kernel<<<dim3(32, 32), 256, 0, stream>>>(wo, WOT, 2048);

    gemm_kernel<false, false><<<dim3(16, 64), 256, 0, stream>>>(XB, WQT, (void*)QB, 2048);
    gemm_kernel<false, false><<<dim3(4, 64), 256, 0, stream>>>(XB, WKT, (void*)KB, 512);
    gemm_kernel<false, true ><<<dim3(4, 64), 256, 0, stream>>>(XB, WVT, (void*)VT, 8192);

    attn_kernel<<<dim3(16, 32), 256, 0, stream>>>(QB, KB, VT, ATTN);

    gemm_kernel<true, false><<<dim3(16, 64), 256, 0, stream>>>(ATTN, WOT, (void*)out, 2048);
}

// Round 4
// 582.285 us; speedup vs baseline: 3.0796x; 1.3036x over previous
//
#include <hip/hip_runtime.h>

typedef unsigned short u16;
typedef __attribute__((ext_vector_type(4))) float f32x4;
typedef __attribute__((ext_vector_type(8))) short bf16x8;

#define GLOBAL_AS(p) ((__attribute__((address_space(1))) void*)(void*)(p))
#define LDS_AS(p)    ((__attribute__((address_space(3))) void*)(p))

// ---------- helpers ----------
__device__ inline u16 f2bf(float f) {
    union { float f; unsigned int u; } v; v.f = f;
    unsigned int u = v.u;
    unsigned int r = (u + 0x7fffu + ((u >> 16) & 1u)) >> 16;
    return (u16)r;
}
__device__ inline unsigned pack2(float a, float b) {
    return (unsigned)f2bf(a) | ((unsigned)f2bf(b) << 16);
}

// ---------- fp32 -> bf16 elementwise ----------
__global__ void cvt_kernel(const float* __restrict__ in, u16* __restrict__ out, int n4) {
    int i = blockIdx.x * blockDim.x + threadIdx.x;
    int stride = gridDim.x * blockDim.x;
    for (int idx = i; idx < n4; idx += stride) {
        float4 v = ((const float4*)in)[idx];
        ushort4 o;
        o.x = f2bf(v.x); o.y = f2bf(v.y); o.z = f2bf(v.z); o.w = f2bf(v.w);
        ((ushort4*)out)[idx] = o;
    }
}

// ---------- fp32 [K][N] -> bf16 [N][K] transpose+convert (K fixed 2048) ----------
__global__ void tcvt_kernel(const float* __restrict__ w, u16* __restrict__ wt, int N) {
    __shared__ float tile[64][65];
    int t = threadIdx.x;
    int tx = t & 63, ty = t >> 6;
    int k0 = blockIdx.y * 64, n0 = blockIdx.x * 64;
#pragma unroll
    for (int i = 0; i < 16; ++i)
        tile[ty * 16 + i][tx] = w[(size_t)(k0 + ty * 16 + i) * N + n0 + tx];
    __syncthreads();
#pragma unroll
    for (int i = 0; i < 16; ++i)
        wt[(size_t)(n0 + ty * 16 + i) * 2048 + k0 + tx] = f2bf(tile[tx][ty * 16 + i]);
}

// ---------- bf16 GEMM: C[M,N] = A[M,2048] * Bt[N,2048]^T ----------
template<bool C_F32, bool C_T>
__global__ __launch_bounds__(256, 2) void gemm_kernel(const u16* __restrict__ A,
                                                      const u16* __restrict__ Bt,
                                                      void* __restrict__ Cv, int ldc) {
    __shared__ __align__(16) u16 As[128][40];
    __shared__ __align__(16) u16 Bs[128][40];
    int tid = threadIdx.x;
    int lane = tid & 63, wid = tid >> 6;
    int lr = lane & 15, lg = lane >> 4;
    int wr = wid >> 1, wc = wid & 1;
    size_t m0 = (size_t)blockIdx.y * 128, n0 = (size_t)blockIdx.x * 128;

    int srow = tid >> 2, sg = tid & 3;
    const u16* ga = A + (m0 + srow) * 2048 + sg * 8;
    const u16* gb = Bt + (n0 + srow) * 2048 + sg * 8;

    f32x4 acc[4][4] = {};

    for (int k0 = 0; k0 < 2048; k0 += 32) {
        uint4 va0 = *(const uint4*)(ga + k0);
        uint4 va1 = *(const uint4*)(ga + (size_t)64 * 2048 + k0);
        uint4 vb0 = *(const uint4*)(gb + k0);
        uint4 vb1 = *(const uint4*)(gb + (size_t)64 * 2048 + k0);
        *(uint4*)&As[srow][sg * 8] = va0;
        *(uint4*)&As[srow + 64][sg * 8] = va1;
        *(uint4*)&Bs[srow][sg * 8] = vb0;
        *(uint4*)&Bs[srow + 64][sg * 8] = vb1;
        __syncthreads();
        bf16x8 af[4], bfr[4];
#pragma unroll
        for (int m = 0; m < 4; ++m) af[m] = *(const bf16x8*)&As[wr * 64 + m * 16 + lr][lg * 8];
#pragma unroll
        for (int n = 0; n < 4; ++n) bfr[n] = *(const bf16x8*)&Bs[wc * 64 + n * 16 + lr][lg * 8];
#pragma unroll
        for (int m = 0; m < 4; ++m)
#pragma unroll
            for (int n = 0; n < 4; ++n)
                acc[m][n] = __builtin_amdgcn_mfma_f32_16x16x32_bf16(af[m], bfr[n], acc[m][n], 0, 0, 0);
        __syncthreads();
    }

#pragma unroll
    for (int m = 0; m < 4; ++m)
#pragma unroll
        for (int n = 0; n < 4; ++n)
#pragma unroll
            for (int i = 0; i < 4; ++i) {
                size_t row = m0 + wr * 64 + m * 16 + lg * 4 + i;
                size_t col = n0 + wc * 64 + n * 16 + lr;
                float v = acc[m][n][i];
                size_t off = C_T ? (col * (size_t)ldc + row) : (row * (size_t)ldc + col);
                if (C_F32) ((float*)Cv)[off] = v;
                else       ((u16*)Cv)[off] = f2bf(v);
            }
}

// ---------- causal GQA flash attention ----------
// global_load_lds staging (no reg staging), XOR-swizzled LDS, swapped QK^T,
// fully in-register softmax + P redistribution (no P LDS buffer).
__global__ __launch_bounds__(256, 2) void attn_kernel(const u16* __restrict__ Q,
                                                      const u16* __restrict__ K,
                                                      const u16* __restrict__ Vt,
                                                      u16* __restrict__ O) {
    __shared__ __align__(16) u16 Ks[2][64 * 128];   // [kv 64][d 128], swizzled
    __shared__ __align__(16) u16 Vs[2][128 * 64];   // [d 128][kv 64], swizzled
    int tid = threadIdx.x;
    int lane = tid & 63, w = tid >> 6;
    int lr = lane & 15, lg = lane >> 4;
    int bx = blockIdx.x;                 // 0..15
    int bh = blockIdx.y;                 // 0..31
    int b = bh >> 4, h = bh & 15, hkv = h >> 2;

    const u16* kp = K + (size_t)(b * 4096) * 512 + hkv * 128;
    const u16* vp = Vt + (size_t)(hkv * 128) * 8192 + (size_t)b * 4096;

    const float SCALE = 0.08838834764831845f; // 1/sqrt(128)

    // staging geometry (per-lane constants)
    int kRb = 16 * w + (lane >> 4);      // + 4*q : K row within chunk
    int kcb = (lane & 15) * 16;          // K linear col byte
    int vRb = 32 * w + (lane >> 3);      // + 8*q : V row (= d)
    int vcb = (lane & 7) * 16;           // V linear col byte

    auto stage = [&](int buf, int kv) {
#pragma unroll
        for (int q = 0; q < 4; ++q) {
            int R = kRb + 4 * q;
            int cb = kcb ^ ((R & 7) << 4);               // pre-swizzled source col
            const u16* gp = kp + (size_t)(kv + R) * 512 + (cb >> 1);
            u16* lp = &Ks[buf][(16 * w + 4 * q) * 128];  // wave-uniform base
            __builtin_amdgcn_global_load_lds(GLOBAL_AS(gp), LDS_AS(lp), 16, 0, 0);
        }
#pragma unroll
        for (int q = 0; q < 4; ++q) {
            int R = vRb + 8 * q;
            int cb = vcb ^ ((R & 7) << 4);
            const u16* gp = vp + (size_t)R * 8192 + kv + (cb >> 1);
            u16* lp = &Vs[buf][(32 * w + 8 * q) * 64];
            __builtin_amdgcn_global_load_lds(GLOBAL_AS(gp), LDS_AS(lp), 16, 0, 0);
        }
    };

    for (int half = 0; half < 2; ++half) {
        int qt = half ? (31 - bx) : bx;
        int q0 = qt * 128;
        int nc = 2 * qt + 2;
        int qb0 = q0 + w * 32;

        // Q fragments: 32 rows per wave (two 16-row tiles)
        bf16x8 qf[2][4];
#pragma unroll
        for (int rt = 0; rt < 2; ++rt) {
            const u16* qp = Q + (size_t)(b * 4096 + qb0 + rt * 16) * 2048 + h * 128;
#pragma unroll
            for (int kk = 0; kk < 4; ++kk)
                qf[rt][kk] = *(const bf16x8*)(qp + (size_t)lr * 2048 + kk * 32 + lg * 8);
        }

        float m_[2] = { -1e30f, -1e30f };
        float s_[2] = { 0.f, 0.f };
        f32x4 oacc[2][8] = {};

        stage(0, 0);
        asm volatile("s_waitcnt vmcnt(0)" ::: "memory");
        __syncthreads();

        int cur = 0;
        for (int c = 0; c < nc; ++c) {
            int kv0 = c * 64;
            if (c + 1 < nc) stage(cur ^ 1, kv0 + 64);

            bool act1 = (kv0 <= qb0 + 31);
            bool act0 = (kv0 <= qb0 + 15);
            if (act1) {
                // ---- QK^T (swapped: A=K, B=Q) -> S[k=lg*4+i (+nt*16)][q=lr]
                f32x4 sacc[2][4] = {};
#pragma unroll
                for (int kk = 0; kk < 4; ++kk) {
                    bf16x8 kf[4];
#pragma unroll
                    for (int nt = 0; nt < 4; ++nt) {
                        int row = nt * 16 + lr;
                        int cb = (kk * 64 + lg * 16) ^ ((lr & 7) << 4);
                        kf[nt] = *(const bf16x8*)&Ks[cur][row * 128 + (cb >> 1)];
                    }
                    if (act0)
#pragma unroll
                        for (int nt = 0; nt < 4; ++nt)
                            sacc[0][nt] = __builtin_amdgcn_mfma_f32_16x16x32_bf16(kf[nt], qf[0][kk], sacc[0][nt], 0, 0, 0);
#pragma unroll
                    for (int nt = 0; nt < 4; ++nt)
                        sacc[1][nt] = __builtin_amdgcn_mfma_f32_16x16x32_bf16(kf[nt], qf[1][kk], sacc[1][nt], 0, 0, 0);
                }

                // ---- softmax + pack + redistribute (per rt), all in-register
                unsigned paw[2][2][4];
#pragma unroll
                for (int rt = 0; rt < 2; ++rt) {
                    if (rt == 0 && !act0) continue;
                    int qb = qb0 + rt * 16;
                    bool need_mask = (kv0 + 63 > qb);
                    float pe[4][4];
                    float cm = -1e30f;
#pragma unroll
                    for (int nt = 0; nt < 4; ++nt)
#pragma unroll
                        for (int i = 0; i < 4; ++i) {
                            float v = sacc[rt][nt][i] * SCALE;
                            if (need_mask && (kv0 + nt * 16 + lg * 4 + i > qb + lr)) v = -1e30f;
                            pe[nt][i] = v;
                            cm = fmaxf(cm, v);
                        }
                    cm = fmaxf(cm, __shfl_xor(cm, 16));
                    cm = fmaxf(cm, __shfl_xor(cm, 32));
                    float mn = fmaxf(m_[rt], cm);
                    float sp = __expf(m_[rt] - mn);
                    m_[rt] = mn;
                    float rs = 0.f;
#pragma unroll
                    for (int nt = 0; nt < 4; ++nt)
#pragma unroll
                        for (int i = 0; i < 4; ++i) {
                            float e = __expf(pe[nt][i] - mn);
                            pe[nt][i] = e;
                            rs += e;
                        }
                    rs += __shfl_xor(rs, 16);
                    rs += __shfl_xor(rs, 32);
                    s_[rt] = s_[rt] * sp + rs;
#pragma unroll
                    for (int i = 0; i < 4; ++i) {
                        float spv = __shfl(sp, lg * 4 + i);
#pragma unroll
                        for (int dt = 0; dt < 8; ++dt) oacc[rt][dt][i] *= spv;
                    }
                    // pack P to bf16 words: own[nt][w] covers k = nt*16+lg*4 + {0,1} / {2,3}
                    unsigned own[4][2], oth[4][2];
#pragma unroll
                    for (int nt = 0; nt < 4; ++nt) {
                        own[nt][0] = pack2(pe[nt][0], pe[nt][1]);
                        own[nt][1] = pack2(pe[nt][2], pe[nt][3]);
                    }
                    // butterfly 1: xor16 (lg pairs) -> 8-k runs
#pragma unroll
                    for (int nt = 0; nt < 4; ++nt) {
                        oth[nt][0] = (unsigned)__shfl_xor((int)own[nt][0], 16);
                        oth[nt][1] = (unsigned)__shfl_xor((int)own[nt][1], 16);
                    }
                    bool lowlg = ((lg & 1) == 0);
                    unsigned run[4][4];
#pragma unroll
                    for (int nt = 0; nt < 4; ++nt) {
                        run[nt][0] = lowlg ? own[nt][0] : oth[nt][0];
                        run[nt][1] = lowlg ? own[nt][1] : oth[nt][1];
                        run[nt][2] = lowlg ? oth[nt][0] : own[nt][0];
                        run[nt][3] = lowlg ? oth[nt][1] : own[nt][1];
                    }
                    // butterfly 2: xor48, send partner's needed nt, keep/take by parity
                    bool hint = ((lg >> 1) != 0);
                    bool keep = ((lg & 1) == (lg >> 1));
#pragma unroll
                    for (int kk2 = 0; kk2 < 2; ++kk2)
#pragma unroll
                        for (int mm = 0; mm < 4; ++mm) {
                            unsigned send = hint ? run[2 * kk2][mm] : run[2 * kk2 + 1][mm];
                            unsigned got = (unsigned)__shfl_xor((int)send, 48);
                            unsigned mine = hint ? run[2 * kk2 + 1][mm] : run[2 * kk2][mm];
                            paw[rt][kk2][mm] = keep ? mine : got;
                        }
                }

                // ---- PV: oacc[q=lg*4+i][d=dt*16+lr]
#pragma unroll
                for (int kk2 = 0; kk2 < 2; ++kk2) {
                    union { unsigned u[4]; bf16x8 v; } c0, c1;
#pragma unroll
                    for (int mm = 0; mm < 4; ++mm) { c0.u[mm] = paw[0][kk2][mm]; c1.u[mm] = paw[1][kk2][mm]; }
#pragma unroll
                    for (int dt = 0; dt < 8; ++dt) {
                        int row = dt * 16 + lr;
                        int cb = (kk2 * 64 + lg * 16) ^ ((lr & 7) << 4);
                        bf16x8 bv = *(const bf16x8*)&Vs[cur][row * 64 + (cb >> 1)];
                        if (act0) oacc[0][dt] = __builtin_amdgcn_mfma_f32_16x16x32_bf16(c0.v, bv, oacc[0][dt], 0, 0, 0);
                        oacc[1][dt] = __builtin_amdgcn_mfma_f32_16x16x32_bf16(c1.v, bv, oacc[1][dt], 0, 0, 0);
                    }
                }
            }

            asm volatile("s_waitcnt vmcnt(0)" ::: "memory");
            __syncthreads();
            cur ^= 1;
        }

        // ---- epilogue
#pragma unroll
        for (int rt = 0; rt < 2; ++rt) {
            u16* op = O + (size_t)(b * 4096 + qb0 + rt * 16) * 2048 + h * 128;
            float sdiv[4];
#pragma unroll
            for (int i = 0; i < 4; ++i) sdiv[i] = __shfl(s_[rt], lg * 4 + i);
#pragma unroll
            for (int dt = 0; dt < 8; ++dt)
#pragma unroll
                for (int i = 0; i < 4; ++i) {
                    float v = oacc[rt][dt][i] / sdiv[i];
                    op[(size_t)(lg * 4 + i) * 2048 + dt * 16 + lr] = f2bf(v);
                }
        }
    }
}

// ---------- launcher ----------
extern "C" void kernel_launch(void* const* d_in, const int* in_sizes, int n_in,
                              void* d_out, int out_size, void* d_ws, size_t ws_size,
                              hipStream_t stream) {
    const float* x  = (const float*)d_in[0];
    const float* wq = (const float*)d_in[1];
    const float* wk = (const float*)d_in[2];
    const float* wv = (const float*)d_in[3];
    const float* wo = (const float*)d_in[4];
    float* out = (float*)d_out;
    u16* ws = (u16*)d_ws;

    u16* XB  = ws;                        // 16777216  [8192][2048]
    u16* WQT = ws + 16777216;             // 4194304   [2048][2048]
    u16* WKT = WQT + 4194304;             // 1048576   [512][2048]
    u16* WVT = WKT + 1048576;             // 1048576   [512][2048]
    u16* WOT = WVT + 1048576;             // 4194304   [2048][2048]
    u16* QB  = WOT + 4194304;             // 16777216  [8192][2048]
    u16* KB  = QB + 16777216;             // 4194304   [8192][512]
    u16* VT  = KB + 4194304;              // 4194304   [512][8192]
    u16* ATTN = XB;

    cvt_kernel<<<2048, 256, 0, stream>>>(x, XB, 16777216 / 4);
    tcvt_kernel<<<dim3(32, 32), 256, 0, stream>>>(wq, WQT, 2048);
    tcvt_kernel<<<dim3(8, 32), 256, 0, stream>>>(wk, WKT, 512);
    tcvt_kernel<<<dim3(8, 32), 256, 0, stream>>>(wv, WVT, 512);
    tcvt_kernel<<<dim3(32, 32), 256, 0, stream>>>(wo, WOT, 2048);

    gemm_kernel<false, false><<<dim3(16, 64), 256, 0, stream>>>(XB, WQT, (void*)QB, 2048);
    gemm_kernel<false, false><<<dim3(4, 64), 256, 0, stream>>>(XB, WKT, (void*)KB, 512);
    gemm_kernel<false, true ><<<dim3(4, 64), 256, 0, stream>>>(XB, WVT, (void*)VT, 8192);

    attn_kernel<<<dim3(16, 32), 256, 0, stream>>>(QB, KB, VT, ATTN);

    gemm_kernel<true, false><<<dim3(16, 64), 256, 0, stream>>>(ATTN, WOT, (void*)out, 2048);
}

// Round 6
// 503.635 us; speedup vs baseline: 3.5606x; 1.1562x over previous
//
#include <hip/hip_runtime.h>

typedef unsigned short u16;
typedef __attribute__((ext_vector_type(4))) float f32x4;
typedef __attribute__((ext_vector_type(8))) short bf16x8;

#define GLOBAL_AS(p) ((__attribute__((address_space(1))) void*)(void*)(p))
#define LDS_AS(p)    ((__attribute__((address_space(3))) void*)(p))

// ---------- helpers ----------
__device__ inline u16 f2bf(float f) {
    union { float f; unsigned int u; } v; v.f = f;
    unsigned int u = v.u;
    unsigned int r = (u + 0x7fffu + ((u >> 16) & 1u)) >> 16;
    return (u16)r;
}
__device__ inline unsigned cvt_pk2(float lo, float hi) {
    unsigned r;
    asm("v_cvt_pk_bf16_f32 %0, %1, %2" : "=v"(r) : "v"(lo), "v"(hi));
    return r;
}

// ---------- fp32 -> bf16 elementwise ----------
__global__ void cvt_kernel(const float* __restrict__ in, u16* __restrict__ out, int n4) {
    int i = blockIdx.x * blockDim.x + threadIdx.x;
    int stride = gridDim.x * blockDim.x;
    for (int idx = i; idx < n4; idx += stride) {
        float4 v = ((const float4*)in)[idx];
        ushort4 o;
        o.x = f2bf(v.x); o.y = f2bf(v.y); o.z = f2bf(v.z); o.w = f2bf(v.w);
        ((ushort4*)out)[idx] = o;
    }
}

// ---------- fp32 [K][N] -> bf16 [N][K] transpose+convert (K fixed 2048) ----------
__global__ void tcvt_kernel(const float* __restrict__ w, u16* __restrict__ wt, int N) {
    __shared__ float tile[64][65];
    int t = threadIdx.x;
    int tx = t & 63, ty = t >> 6;
    int k0 = blockIdx.y * 64, n0 = blockIdx.x * 64;
#pragma unroll
    for (int i = 0; i < 16; ++i)
        tile[ty * 16 + i][tx] = w[(size_t)(k0 + ty * 16 + i) * N + n0 + tx];
    __syncthreads();
#pragma unroll
    for (int i = 0; i < 16; ++i)
        wt[(size_t)(n0 + ty * 16 + i) * 2048 + k0 + tx] = f2bf(tile[tx][ty * 16 + i]);
}

// ---------- bf16 GEMM: C[M,N] = cscale * A[M,2048] * Bt[N,2048]^T ----------
template<bool C_F32, bool C_T>
__global__ __launch_bounds__(256, 2) void gemm_kernel(const u16* __restrict__ A,
                                                      const u16* __restrict__ Bt,
                                                      void* __restrict__ Cv, int ldc,
                                                      float cscale) {
    __shared__ __align__(16) u16 As[128][40];
    __shared__ __align__(16) u16 Bs[128][40];
    int tid = threadIdx.x;
    int lane = tid & 63, wid = tid >> 6;
    int lr = lane & 15, lg = lane >> 4;
    int wr = wid >> 1, wc = wid & 1;
    size_t m0 = (size_t)blockIdx.y * 128, n0 = (size_t)blockIdx.x * 128;

    int srow = tid >> 2, sg = tid & 3;
    const u16* ga = A + (m0 + srow) * 2048 + sg * 8;
    const u16* gb = Bt + (n0 + srow) * 2048 + sg * 8;

    f32x4 acc[4][4] = {};

    for (int k0 = 0; k0 < 2048; k0 += 32) {
        uint4 va0 = *(const uint4*)(ga + k0);
        uint4 va1 = *(const uint4*)(ga + (size_t)64 * 2048 + k0);
        uint4 vb0 = *(const uint4*)(gb + k0);
        uint4 vb1 = *(const uint4*)(gb + (size_t)64 * 2048 + k0);
        *(uint4*)&As[srow][sg * 8] = va0;
        *(uint4*)&As[srow + 64][sg * 8] = va1;
        *(uint4*)&Bs[srow][sg * 8] = vb0;
        *(uint4*)&Bs[srow + 64][sg * 8] = vb1;
        __syncthreads();
        bf16x8 af[4], bfr[4];
#pragma unroll
        for (int m = 0; m < 4; ++m) af[m] = *(const bf16x8*)&As[wr * 64 + m * 16 + lr][lg * 8];
#pragma unroll
        for (int n = 0; n < 4; ++n) bfr[n] = *(const bf16x8*)&Bs[wc * 64 + n * 16 + lr][lg * 8];
#pragma unroll
        for (int m = 0; m < 4; ++m)
#pragma unroll
            for (int n = 0; n < 4; ++n)
                acc[m][n] = __builtin_amdgcn_mfma_f32_16x16x32_bf16(af[m], bfr[n], acc[m][n], 0, 0, 0);
        __syncthreads();
    }

#pragma unroll
    for (int m = 0; m < 4; ++m)
#pragma unroll
        for (int n = 0; n < 4; ++n)
#pragma unroll
            for (int i = 0; i < 4; ++i) {
                size_t row = m0 + wr * 64 + m * 16 + lg * 4 + i;
                size_t col = n0 + wc * 64 + n * 16 + lr;
                float v = acc[m][n][i] * cscale;
                size_t off = C_T ? (col * (size_t)ldc + row) : (row * (size_t)ldc + col);
                if (C_F32) ((float*)Cv)[off] = v;
                else       ((u16*)Cv)[off] = f2bf(v);
            }
}

// ---------- causal GQA flash attention ----------
// global_load_lds staging, XOR-swizzled LDS, swapped QK^T, in-register softmax,
// cvt_pk packing + post-shuffle-select P redistribution, defer-rescale (THR=8).
__global__ __launch_bounds__(256, 2) void attn_kernel(const u16* __restrict__ Q,
                                                      const u16* __restrict__ K,
                                                      const u16* __restrict__ Vt,
                                                      u16* __restrict__ O) {
    __shared__ __align__(16) u16 Ks[2][64 * 128];   // [kv 64][d 128], swizzled
    __shared__ __align__(16) u16 Vs[2][128 * 64];   // [d 128][kv 64], swizzled
    int tid = threadIdx.x;
    int lane = tid & 63, w = tid >> 6;
    int lr = lane & 15, lg = lane >> 4;
    int bx = blockIdx.x;                 // 0..15
    int bh = blockIdx.y;                 // 0..31
    int b = bh >> 4, h = bh & 15, hkv = h >> 2;

    const u16* kp = K + (size_t)(b * 4096) * 512 + hkv * 128;
    const u16* vp = Vt + (size_t)(hkv * 128) * 8192 + (size_t)b * 4096;

    // staging geometry
    int kRb = 16 * w + (lane >> 4);
    int kcb = (lane & 15) * 16;
    int vRb = 32 * w + (lane >> 3);
    int vcb = (lane & 7) * 16;

    auto stage = [&](int buf, int kv) {
#pragma unroll
        for (int q = 0; q < 4; ++q) {
            int R = kRb + 4 * q;
            int cb = kcb ^ ((R & 7) << 4);
            const u16* gp = kp + (size_t)(kv + R) * 512 + (cb >> 1);
            u16* lp = &Ks[buf][(16 * w + 4 * q) * 128];
            __builtin_amdgcn_global_load_lds(GLOBAL_AS(gp), LDS_AS(lp), 16, 0, 0);
        }
#pragma unroll
        for (int q = 0; q < 4; ++q) {
            int R = vRb + 8 * q;
            int cb = vcb ^ ((R & 7) << 4);
            const u16* gp = vp + (size_t)R * 8192 + kv + (cb >> 1);
            u16* lp = &Vs[buf][(32 * w + 8 * q) * 64];
            __builtin_amdgcn_global_load_lds(GLOBAL_AS(gp), LDS_AS(lp), 16, 0, 0);
        }
    };

    for (int half = 0; half < 2; ++half) {
        int qt = half ? (31 - bx) : bx;
        int q0 = qt * 128;
        int nc = 2 * qt + 2;
        int qb0 = q0 + w * 32;

        bf16x8 qf[2][4];
#pragma unroll
        for (int rt = 0; rt < 2; ++rt) {
            const u16* qp = Q + (size_t)(b * 4096 + qb0 + rt * 16) * 2048 + h * 128;
#pragma unroll
            for (int kk = 0; kk < 4; ++kk)
                qf[rt][kk] = *(const bf16x8*)(qp + (size_t)lr * 2048 + kk * 32 + lg * 8);
        }

        float m_[2] = { -1e30f, -1e30f };
        float s_[2] = { 0.f, 0.f };
        f32x4 oacc[2][8] = {};

        stage(0, 0);
        asm volatile("s_waitcnt vmcnt(0)" ::: "memory");
        __syncthreads();

        int cur = 0;
        for (int c = 0; c < nc; ++c) {
            int kv0 = c * 64;
            if (c + 1 < nc) stage(cur ^ 1, kv0 + 64);

            bool act1 = (kv0 <= qb0 + 31);
            bool act0 = (kv0 <= qb0 + 15);
            if (act1) {
                // ---- QK^T (swapped: A=K, B=Q) -> S[k=nt*16+lg*4+i][q=lr]
                f32x4 sacc[2][4] = {};
                __builtin_amdgcn_s_setprio(1);
#pragma unroll
                for (int kk = 0; kk < 4; ++kk) {
                    bf16x8 kf[4];
#pragma unroll
                    for (int nt = 0; nt < 4; ++nt) {
                        int row = nt * 16 + lr;
                        int cb = (kk * 64 + lg * 16) ^ ((lr & 7) << 4);
                        kf[nt] = *(const bf16x8*)&Ks[cur][row * 128 + (cb >> 1)];
                    }
                    if (act0)
#pragma unroll
                        for (int nt = 0; nt < 4; ++nt)
                            sacc[0][nt] = __builtin_amdgcn_mfma_f32_16x16x32_bf16(kf[nt], qf[0][kk], sacc[0][nt], 0, 0, 0);
#pragma unroll
                    for (int nt = 0; nt < 4; ++nt)
                        sacc[1][nt] = __builtin_amdgcn_mfma_f32_16x16x32_bf16(kf[nt], qf[1][kk], sacc[1][nt], 0, 0, 0);
                }
                __builtin_amdgcn_s_setprio(0);

                // ---- softmax (in-register, defer-rescale) + pack + redistribute
                unsigned paw[2][2][4];
#pragma unroll
                for (int rt = 0; rt < 2; ++rt) {
                    if (rt == 0 && !act0) continue;
                    int qb = qb0 + rt * 16;
                    bool need_mask = (kv0 + 63 > qb);
                    float pe[4][4];
                    float cm = -1e30f;
                    if (need_mask) {
#pragma unroll
                        for (int nt = 0; nt < 4; ++nt)
#pragma unroll
                            for (int i = 0; i < 4; ++i) {
                                float v = sacc[rt][nt][i];
                                if (kv0 + nt * 16 + lg * 4 + i > qb + lr) v = -1e30f;
                                pe[nt][i] = v;
                                cm = fmaxf(cm, v);
                            }
                    } else {
#pragma unroll
                        for (int nt = 0; nt < 4; ++nt)
#pragma unroll
                            for (int i = 0; i < 4; ++i) {
                                float v = sacc[rt][nt][i];
                                pe[nt][i] = v;
                                cm = fmaxf(cm, v);
                            }
                    }
                    cm = fmaxf(cm, __shfl_xor(cm, 16));
                    cm = fmaxf(cm, __shfl_xor(cm, 32));
                    // defer-rescale: only rescale when row max grew by > 8
                    if (!__all(cm <= m_[rt] + 8.0f)) {
                        float mn2 = fmaxf(m_[rt], cm);
                        float sp = __expf(m_[rt] - mn2);
                        m_[rt] = mn2;
                        s_[rt] *= sp;
#pragma unroll
                        for (int i = 0; i < 4; ++i) {
                            float spv = __shfl(sp, lg * 4 + i);
#pragma unroll
                            for (int dt = 0; dt < 8; ++dt) oacc[rt][dt][i] *= spv;
                        }
                    }
                    float mn = m_[rt];
                    float rs = 0.f;
#pragma unroll
                    for (int nt = 0; nt < 4; ++nt)
#pragma unroll
                        for (int i = 0; i < 4; ++i) {
                            float e = __expf(pe[nt][i] - mn);
                            pe[nt][i] = e;
                            rs += e;
                        }
                    rs += __shfl_xor(rs, 16);
                    rs += __shfl_xor(rs, 32);
                    s_[rt] += rs;

                    // pack (RNE)
                    unsigned own[4][2];
#pragma unroll
                    for (int nt = 0; nt < 4; ++nt) {
                        own[nt][0] = cvt_pk2(pe[nt][0], pe[nt][1]);
                        own[nt][1] = cvt_pk2(pe[nt][2], pe[nt][3]);
                    }
                    // redistribute: paw[kk2][mm] = own[2kk2+(lg>>1)][mm&1]
                    //   from lane lr + 32*(lg&1) + 16*(mm>>1).
                    // Shuffle BOTH nt candidates, select post-shuffle by target hi2
                    // (R5 bug: pre-shuffle select used the source lane's hi2).
                    bool hi2 = (lg >> 1) != 0;
                    int src01 = ((lg & 1) << 5) + lr;
                    int src23 = src01 + 16;
#pragma unroll
                    for (int kk2 = 0; kk2 < 2; ++kk2) {
                        unsigned a0 = (unsigned)__shfl((int)own[2 * kk2][0], src01);
                        unsigned b0 = (unsigned)__shfl((int)own[2 * kk2 + 1][0], src01);
                        unsigned a1 = (unsigned)__shfl((int)own[2 * kk2][1], src01);
                        unsigned b1 = (unsigned)__shfl((int)own[2 * kk2 + 1][1], src01);
                        unsigned a2 = (unsigned)__shfl((int)own[2 * kk2][0], src23);
                        unsigned b2 = (unsigned)__shfl((int)own[2 * kk2 + 1][0], src23);
                        unsigned a3 = (unsigned)__shfl((int)own[2 * kk2][1], src23);
                        unsigned b3 = (unsigned)__shfl((int)own[2 * kk2 + 1][1], src23);
                        paw[rt][kk2][0] = hi2 ? b0 : a0;
                        paw[rt][kk2][1] = hi2 ? b1 : a1;
                        paw[rt][kk2][2] = hi2 ? b2 : a2;
                        paw[rt][kk2][3] = hi2 ? b3 : a3;
                    }
                }

                // ---- PV: oacc[q=lg*4+i][d=dt*16+lr]
                __builtin_amdgcn_s_setprio(1);
#pragma unroll
                for (int kk2 = 0; kk2 < 2; ++kk2) {
                    union { unsigned u[4]; bf16x8 v; } c0, c1;
#pragma unroll
                    for (int mm = 0; mm < 4; ++mm) { c0.u[mm] = paw[0][kk2][mm]; c1.u[mm] = paw[1][kk2][mm]; }
#pragma unroll
                    for (int dt = 0; dt < 8; ++dt) {
                        int row = dt * 16 + lr;
                        int cb = (kk2 * 64 + lg * 16) ^ ((lr & 7) << 4);
                        bf16x8 bv = *(const bf16x8*)&Vs[cur][row * 64 + (cb >> 1)];
                        if (act0) oacc[0][dt] = __builtin_amdgcn_mfma_f32_16x16x32_bf16(c0.v, bv, oacc[0][dt], 0, 0, 0);
                        oacc[1][dt] = __builtin_amdgcn_mfma_f32_16x16x32_bf16(c1.v, bv, oacc[1][dt], 0, 0, 0);
                    }
                }
                __builtin_amdgcn_s_setprio(0);
            }

            asm volatile("s_waitcnt vmcnt(0)" ::: "memory");
            __syncthreads();
            cur ^= 1;
        }

        // ---- epilogue
#pragma unroll
        for (int rt = 0; rt < 2; ++rt) {
            u16* op = O + (size_t)(b * 4096 + qb0 + rt * 16) * 2048 + h * 128;
            float sdiv[4];
#pragma unroll
            for (int i = 0; i < 4; ++i) sdiv[i] = __shfl(s_[rt], lg * 4 + i);
#pragma unroll
            for (int dt = 0; dt < 8; ++dt)
#pragma unroll
                for (int i = 0; i < 4; ++i) {
                    float v = oacc[rt][dt][i] / sdiv[i];
                    op[(size_t)(lg * 4 + i) * 2048 + dt * 16 + lr] = f2bf(v);
                }
        }
    }
}

// ---------- launcher ----------
extern "C" void kernel_launch(void* const* d_in, const int* in_sizes, int n_in,
                              void* d_out, int out_size, void* d_ws, size_t ws_size,
                              hipStream_t stream) {
    const float* x  = (const float*)d_in[0];
    const float* wq = (const float*)d_in[1];
    const float* wk = (const float*)d_in[2];
    const float* wv = (const float*)d_in[3];
    const float* wo = (const float*)d_in[4];
    float* out = (float*)d_out;
    u16* ws = (u16*)d_ws;

    u16* XB  = ws;                        // 16777216  [8192][2048]
    u16* WQT = ws + 16777216;             // 4194304   [2048][2048]
    u16* WKT = WQT + 4194304;             // 1048576   [512][2048]
    u16* WVT = WKT + 1048576;             // 1048576   [512][2048]
    u16* WOT = WVT + 1048576;             // 4194304   [2048][2048]
    u16* QB  = WOT + 4194304;             // 16777216  [8192][2048]
    u16* KB  = QB + 16777216;             // 4194304   [8192][512]
    u16* VT  = KB + 4194304;              // 4194304   [512][8192]
    u16* ATTN = XB;

    const float SCALE = 0.08838834764831845f; // 1/sqrt(128), folded into Q proj

    cvt_kernel<<<2048, 256, 0, stream>>>(x, XB, 16777216 / 4);
    tcvt_kernel<<<dim3(32, 32), 256, 0, stream>>>(wq, WQT, 2048);
    tcvt_kernel<<<dim3(8, 32), 256, 0, stream>>>(wk, WKT, 512);
    tcvt_kernel<<<dim3(8, 32), 256, 0, stream>>>(wv, WVT, 512);
    tcvt_kernel<<<dim3(32, 32), 256, 0, stream>>>(wo, WOT, 2048);

    gemm_kernel<false, false><<<dim3(16, 64), 256, 0, stream>>>(XB, WQT, (void*)QB, 2048, SCALE);
    gemm_kernel<false, false><<<dim3(4, 64), 256, 0, stream>>>(XB, WKT, (void*)KB, 512, 1.0f);
    gemm_kernel<false, true ><<<dim3(4, 64), 256, 0, stream>>>(XB, WVT, (void*)VT, 8192, 1.0f);

    attn_kernel<<<dim3(16, 32), 256, 0, stream>>>(QB, KB, VT, ATTN);

    gemm_kernel<true, false><<<dim3(16, 64), 256, 0, stream>>>(ATTN, WOT, (void*)out, 2048, 1.0f);
}